// Round 13
// baseline (435.019 us; speedup 1.0000x reference)
//
#include <hip/hip_runtime.h>
#include <hip/hip_fp16.h>
#include <stdint.h>

#define K_    367
#define P_    217
#define Q_    721
#define QC    217
#define CPQ   (QC*QC)               // 47089 corner positions
#define YSTR  47104                 // y plane stride (floats), 16B aligned
#define PQ_   (P_*Q_)               // 156457
#define LDSH  47092                 // halfs in LDS (94.2 KB) -> FULL plane coverage
#define NU4C  (217*55)              // 11935 corner quad-units per k (q0 = 4u, u<55)
#define NVT   (109368/4)            // 27342 tail quad-units per k (504%4==0)

#define FILL_LDS() { \
    const float4* s4_ = (const float4*)yplane; \
    __half2* d2_ = (__half2*)ylds; \
    for (int i_ = threadIdx.x; i_ < LDSH / 4; i_ += 1024) { \
        float4 v_ = s4_[i_]; \
        d2_[2 * i_]     = __floats2half2_rn(v_.x, v_.y); \
        d2_[2 * i_ + 1] = __floats2half2_rn(v_.z, v_.w); \
    } }

// ---------- setup: y0 corner copy (both batches) + zero y1..y4 + zero out
__global__ __launch_bounds__(256) void setup_all(
    const float* __restrict__ inp, float* __restrict__ ybase,
    float* __restrict__ out)
{
    long long id = (long long)blockIdx.x * 256 + threadIdx.x;
    if (id < CPQ) {
        int o = (int)id;
        int p = o / QC, q = o - p * QC;
        ybase[o]        = inp[p * 256 + q];
        ybase[YSTR + o] = inp[65536 + p * 256 + q];
        return;
    }
    long long e = id - CPQ;
    if (e < 8 * YSTR) { ybase[2 * YSTR + e] = 0.f; return; }   // y1..y4
    e -= 8 * YSTR;
    if (e < 2 * PQ_) out[e] = 0.f;
}

// ---------- corner iteration, RAW ind/w (no pack).
// grid (120,1,2), KS=10: ob=lb%12, kc=lb/12 -> exactly 1 unit/block.
// Unit = quad (p, q0=4u): reads 32B ind + 16B w per k (dense across lanes,
// 207MB footprint -> L3-resident after iter 1). Garbage entries at q>=217
// gather safely (all ind values <217) and are simply not written.
__global__ __launch_bounds__(1024) void iter_raw(
    const int2* __restrict__ ind, const float* __restrict__ w,
    const float* __restrict__ yin, float* __restrict__ yout,
    const float* __restrict__ lam_p, int KS)
{
    __shared__ __half ylds[LDSH];
    const int bz = blockIdx.z;
    const float* __restrict__ yplane = yin + (size_t)bz * YSTR;
    FILL_LDS();
    __syncthreads();
    const float ls = *lam_p;
    int ob = blockIdx.x % 12, kc = blockIdx.x / 12;
    int k0 = kc * K_ / KS, k1 = (kc + 1) * K_ / KS;
    int ov = ob * 1024 + threadIdx.x;
    if (ov >= NU4C) return;
    int p = ov / 55, u = ov - p * 55;
    int q0 = 4 * u;
    long long rawb = (long long)p * Q_ + q0;
    const int2*  ip = ind + (long long)k0 * PQ_ + rawb;
    const float* wp = w   + (long long)k0 * PQ_ + rawb;
    float a0 = 0.f, a1 = 0.f, a2 = 0.f, a3 = 0.f;
    #pragma unroll 4
    for (int k = k0; k < k1; ++k, ip += PQ_, wp += PQ_) {
        int4 ia, ib; float4 wv;
        __builtin_memcpy(&ia, ip, 16);
        __builtin_memcpy(&ib, ip + 2, 16);
        __builtin_memcpy(&wv, wp, 16);
        a0 = fmaf(wv.x, __half2float(ylds[ia.x * QC + ia.y]), a0);
        a1 = fmaf(wv.y, __half2float(ylds[ia.z * QC + ia.w]), a1);
        a2 = fmaf(wv.z, __half2float(ylds[ib.x * QC + ib.y]), a2);
        a3 = fmaf(wv.w, __half2float(ylds[ib.z * QC + ib.w]), a3);
    }
    float acc[4] = {a0, a1, a2, a3};
    int nv = QC - q0; if (nv > 4) nv = 4;       // 4 except last unit (1)
    float* op = yout + (size_t)bz * YSTR + p * QC + q0;
    for (int j = 0; j < nv; ++j) atomicAdd(op + j, acc[j] * ls);
}

// ---------- final, corner half: same raw quad pattern, outputs to out[b][p][q0+j].
// Runs BEFORE final_t so the corner region is still L3-hot.
__global__ __launch_bounds__(1024) void final_corner(
    const int2* __restrict__ ind, const float* __restrict__ w,
    const float* __restrict__ yin, float* __restrict__ out,
    const float* __restrict__ lam_p, int KS)
{
    __shared__ __half ylds[LDSH];
    const int bz = blockIdx.z;
    const float* __restrict__ yplane = yin + (size_t)bz * YSTR;
    FILL_LDS();
    __syncthreads();
    const float ls = *lam_p;
    int ob = blockIdx.x % 12, kc = blockIdx.x / 12;
    int k0 = kc * K_ / KS, k1 = (kc + 1) * K_ / KS;
    int ov = ob * 1024 + threadIdx.x;
    if (ov >= NU4C) return;
    int p = ov / 55, u = ov - p * 55;
    int q0 = 4 * u;
    long long rawb = (long long)p * Q_ + q0;
    const int2*  ip = ind + (long long)k0 * PQ_ + rawb;
    const float* wp = w   + (long long)k0 * PQ_ + rawb;
    float a0 = 0.f, a1 = 0.f, a2 = 0.f, a3 = 0.f;
    #pragma unroll 4
    for (int k = k0; k < k1; ++k, ip += PQ_, wp += PQ_) {
        int4 ia, ib; float4 wv;
        __builtin_memcpy(&ia, ip, 16);
        __builtin_memcpy(&ib, ip + 2, 16);
        __builtin_memcpy(&wv, wp, 16);
        a0 = fmaf(wv.x, __half2float(ylds[ia.x * QC + ia.y]), a0);
        a1 = fmaf(wv.y, __half2float(ylds[ia.z * QC + ia.w]), a1);
        a2 = fmaf(wv.z, __half2float(ylds[ib.x * QC + ib.y]), a2);
        a3 = fmaf(wv.w, __half2float(ylds[ib.z * QC + ib.w]), a3);
    }
    float acc[4] = {a0, a1, a2, a3};
    int nv = QC - q0; if (nv > 4) nv = 4;
    float* op = out + (size_t)bz * PQ_ + (long long)p * Q_ + q0;
    for (int j = 0; j < nv; ++j) atomicAdd(op + j, acc[j] * ls);
}

// ---------- final, tail half: raw ind/w streamed once from HBM.
// grid (126,1,2), KS=14: 27*14=378 units -> exactly 3 units/block.
__global__ __launch_bounds__(1024) void final_tail(
    const int2* __restrict__ ind, const float* __restrict__ w,
    const float* __restrict__ yin, float* __restrict__ out,
    const float* __restrict__ lam_p, int KS)
{
    __shared__ __half ylds[LDSH];
    const int bz = blockIdx.z;
    const float* __restrict__ yplane = yin + (size_t)bz * YSTR;
    FILL_LDS();
    __syncthreads();
    const float ls = *lam_p;
    for (int uu = 0; uu < 3; ++uu) {
        int unit = blockIdx.x + uu * 126;         // 0..377
        int ob = unit % 27, kc = unit / 27;
        int k0 = kc * K_ / KS, k1 = (kc + 1) * K_ / KS;
        int ov = ob * 1024 + threadIdx.x;
        if (ov >= NVT) continue;
        int t = 4 * ov;                           // tail position, 504%4==0
        int p = t / 504;
        int q2 = t - p * 504;
        long long rawb = (long long)p * Q_ + QC + q2;
        const int2*  ip = ind + (long long)k0 * PQ_ + rawb;
        const float* wp = w   + (long long)k0 * PQ_ + rawb;
        float a0 = 0.f, a1 = 0.f, a2 = 0.f, a3 = 0.f;
        #pragma unroll 4
        for (int k = k0; k < k1; ++k, ip += PQ_, wp += PQ_) {
            int4 ia, ib; float4 wv;
            __builtin_memcpy(&ia, ip, 16);
            __builtin_memcpy(&ib, ip + 2, 16);
            __builtin_memcpy(&wv, wp, 16);
            a0 = fmaf(wv.x, __half2float(ylds[ia.x * QC + ia.y]), a0);
            a1 = fmaf(wv.y, __half2float(ylds[ia.z * QC + ia.w]), a1);
            a2 = fmaf(wv.z, __half2float(ylds[ib.x * QC + ib.y]), a2);
            a3 = fmaf(wv.w, __half2float(ylds[ib.z * QC + ib.w]), a3);
        }
        float acc[4] = {a0, a1, a2, a3};
        float* op = out + (size_t)bz * PQ_ + (long long)p * Q_ + QC + q2;
        #pragma unroll
        for (int j = 0; j < 4; ++j) atomicAdd(op + j, acc[j] * ls);
    }
}

extern "C" void kernel_launch(void* const* d_in, const int* in_sizes, int n_in,
                              void* d_out, int out_size, void* d_ws, size_t ws_size,
                              hipStream_t stream)
{
    const float* inp = (const float*)d_in[0];
    const int2*  ind = (const int2*)d_in[1];
    const float* w1  = (const float*)d_in[2];
    const float* lam = (const float*)d_in[3];
    float* out = (float*)d_out;

    size_t YB = (size_t)(2 * YSTR) * sizeof(float);
    if (ws_size < 5 * YB) return;                 // ws has always been ample

    float* ybase = (float*)d_ws;
    float* y[5];
    for (int i = 0; i < 5; ++i) y[i] = ybase + (size_t)i * (2 * YSTR);

    // setup: y0 copy + zero y1..y4 + zero out
    long long nwork = CPQ + 8LL * YSTR + 2LL * PQ_;
    unsigned nb = (unsigned)((nwork + 255) / 256);
    setup_all<<<dim3(nb), 256, 0, stream>>>(inp, ybase, out);

    dim3 gC(120, 1, 2), gT(126, 1, 2);
    for (int it = 0; it < 4; ++it)
        iter_raw<<<gC, 1024, 0, stream>>>(ind, w1, y[it], y[it + 1], lam, 10);
    final_corner<<<gC, 1024, 0, stream>>>(ind, w1, y[4], out, lam, 10);
    final_tail<<<gT, 1024, 0, stream>>>(ind, w1, y[4], out, lam, 14);
}